// Round 17
// baseline (56.088 us; speedup 1.0000x reference)
//
#include <hip/hip_runtime.h>

// FeatureAttentionLayer: B=32, W=128, K=128, E=256, fp32 — FUSED v2 (r16 parts).
//   L[i][e] = sum_w x[b][w][i]*lin_w[e][w] + lin_b[e]
//   R[j][e] = sum_w x[b][w][j]*lin_w[e][128+w]
//   e[i][j] = 0.6(dL[i]+dR[j]) + sum_e 0.4a[e]|L+R| + bias   (LReLU identity)
//   att = softmax_j; out[b][w][i] = sigmoid(sum_j att[i][j]*x[b][w][j])
//
// Round-17: fuse the r16-proven structures (r13's fused failure predates the
// e-split e-loop, MFMA-PV, and 8-wave TLP). Per (b,it) block, 512 thr:
//   stage xT bf16 once -> per 64-e chunk {reg-prefetch lin_w -> bf16 AS ->
//   MFMA R(64ex128j, 8-way split)+L(+lin_b) -> e-split e-loop} -> partials ->
//   softmax -> MFMA-PV. Eliminates K1 launch, P round-trip, Ps bounce, RLOAD
//   prologue. Adds 8x redundant R-MFMA (~0.3us) + lin_w re-read (L2, hidden).
// No workspace. 11 barriers. 119.5 KB LDS, 1 block/CU = 2 waves/SIMD.

typedef float v2f __attribute__((ext_vector_type(2)));
typedef float v4f __attribute__((ext_vector_type(4)));
typedef short bf16x8 __attribute__((ext_vector_type(8)));

__device__ __forceinline__ unsigned pack_bf16x2(float a, float b) {
    unsigned ua = __builtin_bit_cast(unsigned, a);
    unsigned ub = __builtin_bit_cast(unsigned, b);
    ua = (ua + 0x7FFFu + ((ua >> 16) & 1u)) >> 16;   // RNE f32->bf16
    ub = (ub + 0x7FFFu + ((ub >> 16) & 1u)) >> 16;
    return ua | (ub << 16);
}

// S layout (f32 idx):
//   XT   0      u16[128*136] bf16 x^T swizzled (8704 f32)
//   AS   8704   u16[64*264]  bf16 lin_w chunk  (8448 f32)
//   RS   17152  f32[64*132]  R chunk           (8448)
//   LTC  25600  f32[64*20]   L chunk (+lin_b)  (1280)
//   A6 26880 | A4 27136 | LBS 27392 | DLR 27648 (8x16) | DRR 27776 (8x128)
//   ATT  28800  u32[16*68]   att bf16 pairs    (1088)
// overlays: red f32[8][16][128] @ 8704 (dead AS+RS); xbf u32[128*68] @ 0 (dead XT)
#define XT   0
#define AS   8704
#define RS   17152
#define LTC  25600
#define A6   26880
#define A4   27136
#define LBS  27392
#define DLR  27648
#define DRR  27776
#define ATT  28800
#define SSZ  29888

__global__ __launch_bounds__(512) void k_fused(
    const float* __restrict__ x, const float* __restrict__ lin_w,
    const float* __restrict__ lin_b, const float* __restrict__ a,
    const float* __restrict__ bias, float* __restrict__ out)
{
    __shared__ __align__(16) float S[SSZ];   // 119.5 KB

    const int t = threadIdx.x;
    const int b = blockIdx.x, it = blockIdx.y;

    unsigned short* xtu = (unsigned short*)&S[XT];
    unsigned*       asu32 = (unsigned*)&S[AS];
    const unsigned short* asu = (const unsigned short*)&S[AS];

    // ---- lin_w chunk prefetch: 64 rows x 256 cols = 8 v4f/thread ----
    v4f pre[8];
#define WLOAD(c_) do {                                                       \
    _Pragma("unroll") for (int q = 0; q < 8; ++q) {                          \
        const int idx = t + q * 512;                                         \
        const int rr = idx >> 6, cp = idx & 63;                              \
        pre[q] = *(const v4f*)(lin_w + (size_t)((c_) * 64 + rr) * 256 + cp * 4); \
    } } while (0)

#define COMMIT() do {                                                        \
    _Pragma("unroll") for (int q = 0; q < 8; ++q) {                          \
        const int idx = t + q * 512;                                         \
        const int rr = idx >> 6, cp = idx & 63;                              \
        uint2 pk;                                                            \
        pk.x = pack_bf16x2(pre[q][0], pre[q][1]);                            \
        pk.y = pack_bf16x2(pre[q][2], pre[q][3]);                            \
        *(uint2*)&asu32[rr * 132 + cp * 2] = pk; } } while (0)

    WLOAD(0);

    // ---- stage xT[k][w'] = bf16(x[b][w][k]), swizzle g ^= (k>>3)&15 ----
    {
        const float* xg = x + b * 16384;
        #pragma unroll
        for (int q = 0; q < 4; ++q) {
            const int idx = t + q * 512;                 // 0..2047
            const int wp = idx >> 5;                     // w-pair 0..63
            const int k4 = (idx & 31) << 2;
            const v4f r0v = *(const v4f*)(xg + (2 * wp) * 128 + k4);
            const v4f r1v = *(const v4f*)(xg + (2 * wp + 1) * 128 + k4);
            const int g   = wp >> 2;
            const int off = (2 * wp) & 7;
            #pragma unroll
            for (int u = 0; u < 4; ++u) {
                const int k = k4 + u;
                const int gs = g ^ ((k >> 3) & 15);
                *(unsigned*)&xtu[k * 136 + (gs << 3) + off] = pack_bf16x2(r0v[u], r1v[u]);
            }
        }
    }
    if (t < 256) {
        S[A6 + t]  = 0.6f * a[t];
        S[A4 + t]  = 0.4f * a[t];
        S[LBS + t] = lin_b[t];
    }
    COMMIT();                  // chunk 0 -> AS
    WLOAD(1);
    __syncthreads();           // xT + AS0 + tables ready

    const int l = t & 63, wv = t >> 6;
    const int lr = l & 15, lg = l >> 4;
    const int jl = l & 31, il = l >> 5;
    const int j0e = jl * 4;
    const int eg4 = wv >> 1;                   // production e-group (16 e)
    const int jh  = wv & 1;                    // production j-half (64 j)

    float acc[8][4] = {};                      // [i-sub][jj] 0.4a*|L+R|
    float dle[8] = {};                         // 0.6a*L per i-sub
    float dre[4] = {};                         // 0.6a*R per jj
    v4f xr[8];                                 // late x reload for PV

    #pragma unroll 1
    for (int c = 0; c < 4; ++c) {
        // ---- MFMA: produce R chunk (wave: 16e x 64j) + L (even waves) ----
        {
            bf16x8 afR[4];
            #pragma unroll
            for (int kc = 0; kc < 4; ++kc)
                afR[kc] = *(const bf16x8*)&asu[(eg4 * 16 + lr) * 264 + 128 + kc * 32 + lg * 8];
            v4f aR[4];
            #pragma unroll
            for (int nf = 0; nf < 4; ++nf) aR[nf] = (v4f){0.f, 0.f, 0.f, 0.f};
            #pragma unroll
            for (int nf = 0; nf < 4; ++nf) {
                const int row = jh * 64 + nf * 16 + lr;
                const int vr = (row >> 3) & 15;
                #pragma unroll
                for (int kc = 0; kc < 4; ++kc) {
                    const bf16x8 bv = *(const bf16x8*)&xtu[row * 136 + (((kc * 4 + lg) ^ vr) << 3)];
                    aR[nf] = __builtin_amdgcn_mfma_f32_16x16x32_bf16(afR[kc], bv, aR[nf], 0, 0, 0);
                }
            }
            #pragma unroll
            for (int j = 0; j < 4; ++j) {
                const int el = eg4 * 16 + lg * 4 + j;
                #pragma unroll
                for (int nf = 0; nf < 4; ++nf)
                    S[RS + el * 132 + jh * 64 + nf * 16 + lr] = aR[nf][j];
            }
            if (jh == 0) {                     // L: 16e x 16i for this block
                bf16x8 afL[4];
                #pragma unroll
                for (int kc = 0; kc < 4; ++kc)
                    afL[kc] = *(const bf16x8*)&asu[(eg4 * 16 + lr) * 264 + kc * 32 + lg * 8];
                const int row = it * 16 + lr;
                const int vr = (row >> 3) & 15;
                v4f aL = (v4f){0.f, 0.f, 0.f, 0.f};
                #pragma unroll
                for (int kc = 0; kc < 4; ++kc) {
                    const bf16x8 bv = *(const bf16x8*)&xtu[row * 136 + (((kc * 4 + lg) ^ vr) << 3)];
                    aL = __builtin_amdgcn_mfma_f32_16x16x32_bf16(afL[kc], bv, aL, 0, 0, 0);
                }
                #pragma unroll
                for (int j = 0; j < 4; ++j) {
                    const int el = eg4 * 16 + lg * 4 + j;
                    S[LTC + el * 20 + lr] = aL[j] + S[LBS + c * 64 + el];
                }
            }
        }
        __syncthreads();                       // RS/LTC ready; AS reads done

        // ---- e-split e-loop (wave owns 8 e's) ∥ commit next lin_w chunk ----
        #pragma unroll
        for (int g = 0; g < 2; ++g) {
            const int er = wv * 8 + g * 4;
            const int eg = c * 64 + er;
            v4f rv[4], lA[4], lB[4];
            #pragma unroll
            for (int u = 0; u < 4; ++u) {
                rv[u] = *(const v4f*)&S[RS + (er + u) * 132 + j0e];
                lA[u] = *(const v4f*)&S[LTC + (er + u) * 20 + il * 8];
                lB[u] = *(const v4f*)&S[LTC + (er + u) * 20 + il * 8 + 4];
            }
            const v4f a6v = *(const v4f*)&S[A6 + eg];
            const v4f a4v = *(const v4f*)&S[A4 + eg];
            #pragma unroll
            for (int u = 0; u < 4; ++u) {
                const float a6u = a6v[u], a4u = a4v[u];
                #pragma unroll
                for (int q = 0; q < 4; ++q) {
                    const float la = lA[u][q], lb2 = lB[u][q];
                    dle[q]     = fmaf(a6u, la,  dle[q]);
                    dle[4 + q] = fmaf(a6u, lb2, dle[4 + q]);
                    #pragma unroll
                    for (int jj = 0; jj < 4; ++jj) {
                        const float r = rv[u][jj];
                        acc[q][jj]     = fmaf(a4u, fabsf(la  + r), acc[q][jj]);
                        acc[4 + q][jj] = fmaf(a4u, fabsf(lb2 + r), acc[4 + q][jj]);
                    }
                }
                #pragma unroll
                for (int jj = 0; jj < 4; ++jj)
                    dre[jj] = fmaf(a6u, rv[u][jj], dre[jj]);
            }
        }
        if (c < 3) {
            COMMIT();                          // chunk c+1 -> AS (AS free since barrier)
            if (c < 2) WLOAD(c + 2);
            else {                             // last needed lin_w done -> prefetch x for PV
                const float* xg = x + b * 16384;
                #pragma unroll
                for (int q = 0; q < 4; ++q) {
                    const int idx = t + q * 512;
                    const int w = idx >> 4, j8 = (idx & 15) * 8;
                    xr[2 * q]     = *(const v4f*)(xg + w * 128 + j8);
                    xr[2 * q + 1] = *(const v4f*)(xg + w * 128 + j8 + 4);
                }
            }
        }
        __syncthreads();                       // e-loop done (RS free) & AS ready
    }

    // ---- partials -> red[8][16][128] (overlays dead AS+RS) + DLR/DRR ----
    {
        float* red = &S[AS];
        #pragma unroll
        for (int q = 0; q < 8; ++q)
            *(v4f*)&red[wv * 2048 + (il * 8 + q) * 128 + j0e] =
                (v4f){acc[q][0], acc[q][1], acc[q][2], acc[q][3]};
        if (jl == 0) {
            *(v4f*)&S[DLR + wv * 16 + il * 8]     = (v4f){dle[0], dle[1], dle[2], dle[3]};
            *(v4f*)&S[DLR + wv * 16 + il * 8 + 4] = (v4f){dle[4], dle[5], dle[6], dle[7]};
        }
        if (il == 0)
            *(v4f*)&S[DRR + wv * 128 + j0e] = (v4f){dre[0], dre[1], dre[2], dre[3]};
    }
    __syncthreads();                           // red/DLR/DRR ready

    // ---- softmax (i = t>>5, 4 j) -> ATT bf16 ; commit xbf onto dead XT ----
    {
        const int jps = t & 31, i = t >> 5;
        const int j0s = jps * 4;
        const int i0 = it * 16;
        const float* red = &S[AS];
        v4f sm = *(const v4f*)&red[i * 128 + j0s];
        v4f drs = *(const v4f*)&S[DRR + j0s];
        float dls = S[DLR + i];
        #pragma unroll
        for (int es = 1; es < 8; ++es) {
            sm  += *(const v4f*)&red[es * 2048 + i * 128 + j0s];
            drs += *(const v4f*)&S[DRR + es * 128 + j0s];
            dls += S[DLR + es * 16 + i];
        }
        const v4f bi = *(const v4f*)(bias + (i0 + i) * 128 + j0s);
        float ev[4];
        #pragma unroll
        for (int jj = 0; jj < 4; ++jj) ev[jj] = sm[jj] + dls + drs[jj] + bi[jj];
        float m_ = fmaxf(fmaxf(ev[0], ev[1]), fmaxf(ev[2], ev[3]));
        #pragma unroll
        for (int d = 1; d <= 16; d <<= 1) m_ = fmaxf(m_, __shfl_xor(m_, d));
        float p0 = __expf(ev[0] - m_), p1 = __expf(ev[1] - m_);
        float p2 = __expf(ev[2] - m_), p3 = __expf(ev[3] - m_);
        float s_ = p0 + p1 + p2 + p3;
        #pragma unroll
        for (int d = 1; d <= 16; d <<= 1) s_ += __shfl_xor(s_, d);
        const float inv = 1.f / s_;
        unsigned* attu = (unsigned*)&S[ATT];
        attu[i * 68 + jps * 2]     = pack_bf16x2(p0 * inv, p1 * inv);
        attu[i * 68 + jps * 2 + 1] = pack_bf16x2(p2 * inv, p3 * inv);
    }
    {   // xbf[w][j] bf16 commit (XT region is dead after last MFMA chunk)
        unsigned* ubf = (unsigned*)&S[XT];
        #pragma unroll
        for (int q = 0; q < 4; ++q) {
            const int idx = t + q * 512;
            const int w = idx >> 4, jhc = (idx & 15) * 4;
            const v4f x0 = xr[2 * q], x1 = xr[2 * q + 1];
            uint4 pk;
            pk.x = pack_bf16x2(x0[0], x0[1]);  pk.y = pack_bf16x2(x0[2], x0[3]);
            pk.z = pack_bf16x2(x1[0], x1[1]);  pk.w = pack_bf16x2(x1[2], x1[3]);
            *(uint4*)&ubf[w * 68 + jhc] = pk;
        }
    }
    __syncthreads();                           // ATT + xbf ready

    // ---- PV via MFMA: out[w][i] = sum_j att[i][j] x[w][j]; D: m=i, n=w ----
    {
        const unsigned* attu = (const unsigned*)&S[ATT];
        const unsigned* ubf = (const unsigned*)&S[XT];
        const int i0 = it * 16;
        bf16x8 paf[4];
        #pragma unroll
        for (int kc = 0; kc < 4; ++kc)
            paf[kc] = *(const bf16x8*)&attu[lr * 68 + kc * 16 + lg * 4];
        const int wrow = wv * 16 + lr;         // 8 waves x 16 = 128 w
        v4f pacc = (v4f){0.f, 0.f, 0.f, 0.f};
        #pragma unroll
        for (int kc = 0; kc < 4; ++kc) {
            const bf16x8 bv = *(const bf16x8*)&ubf[wrow * 68 + kc * 16 + lg * 4];
            pacc = __builtin_amdgcn_mfma_f32_16x16x32_bf16(paf[kc], bv, pacc, 0, 0, 0);
        }
        v4f r;
        r[0] = 1.f / (1.f + __expf(-pacc[0]));
        r[1] = 1.f / (1.f + __expf(-pacc[1]));
        r[2] = 1.f / (1.f + __expf(-pacc[2]));
        r[3] = 1.f / (1.f + __expf(-pacc[3]));
        *(v4f*)(out + (size_t)b * 16384 + wrow * 128 + i0 + lg * 4) = r;
    }
}

extern "C" void kernel_launch(void* const* d_in, const int* in_sizes, int n_in,
                              void* d_out, int out_size, void* d_ws, size_t ws_size,
                              hipStream_t stream) {
    const float* x     = (const float*)d_in[0];
    const float* lin_w = (const float*)d_in[1];
    const float* lin_b = (const float*)d_in[2];
    const float* a     = (const float*)d_in[3];
    const float* bias  = (const float*)d_in[4];
    float* out = (float*)d_out;
    (void)d_ws; (void)ws_size;

    k_fused<<<dim3(32, 8), 512, 0, stream>>>(x, lin_w, lin_b, a, bias, out);
}

// Round 18
// 28.178 us; speedup vs baseline: 1.9905x; 1.9905x over previous
//
#include <hip/hip_runtime.h>

// FeatureAttentionLayer: B=32, W=128, K=128, E=256, fp32.
//   L[i][e] = sum_w x[b][w][i]*lin_w[e][w] + lin_b[e]
//   R[j][e] = sum_w x[b][w][j]*lin_w[e][128+w]
//   e[i][j] = 0.6(dL[i]+dR[j]) + sum_e 0.4a[e]|L+R| + bias   (LReLU identity)
//   att = softmax_j; out[b][w][i] = sigmoid(sum_j att[i][j]*x[b][w][j])
//
// ws: P[b][r][k] (r<256: L^T rows +lin_b; r>=256: R^T rows); a6/a4 @ 2M.
// Round-18: REVERT to round-16 (best, 25.9us). r17's fusion re-read lin_w
// per block (64MB aggregate, FETCH 28MB latency-bound ~50us) to save a ~10MB
// P round-trip — measured net-negative twice (r12, r17). Fusion lever dead.
// This file == r16 verbatim: K1 = minimal-instruction MFMA GEMM (r14);
// K2 = 512-thr 8-wave e-split + softmax + MFMA-PV.

typedef float v2f __attribute__((ext_vector_type(2)));
typedef float v4f __attribute__((ext_vector_type(4)));
typedef short bf16x8 __attribute__((ext_vector_type(8)));

#define WS_A6  2097152
#define WS_A4  (2097152 + 256)

__device__ __forceinline__ unsigned pack_bf16x2(float a, float b) {
    unsigned ua = __builtin_bit_cast(unsigned, a);
    unsigned ub = __builtin_bit_cast(unsigned, b);
    ua = (ua + 0x7FFFu + ((ua >> 16) & 1u)) >> 16;   // RNE f32->bf16
    ub = (ub + 0x7FFFu + ((ub >> 16) & 1u)) >> 16;
    return ua | (ub << 16);
}

// ---------------- K1: projection GEMM (r14, unchanged) ----------------
__global__ __launch_bounds__(256) void k_linear(
    const float* __restrict__ x, const float* __restrict__ lin_w,
    const float* __restrict__ lin_b, const float* __restrict__ a,
    float* __restrict__ ws)
{
    __shared__ unsigned short xT[64 * 136];
    __shared__ float Ps[64 * 68];

    const int t = threadIdx.x;
    const int b = blockIdx.x, rt = blockIdx.y, kt = blockIdx.z;
    const int r0 = rt * 64, k0 = kt * 64;
    const bool isL = (rt < 4);

    if (b == 0 && rt == 0 && kt == 0) {
        float av = a[t];
        ws[WS_A6 + t] = 0.6f * av;
        ws[WS_A4 + t] = 0.4f * av;
    }

    {
        const float* xg = x + b * 16384 + k0;
        #pragma unroll
        for (int q = 0; q < 4; ++q) {
            const int idx = t + q * 256;
            const int wp = idx >> 4;
            const int k4 = (idx & 15) << 2;
            const v4f r0v = *(const v4f*)(xg + (2 * wp) * 128 + k4);
            const v4f r1v = *(const v4f*)(xg + (2 * wp + 1) * 128 + k4);
            const int g   = wp >> 2;
            const int off = (2 * wp) & 7;
            #pragma unroll
            for (int u = 0; u < 4; ++u) {
                const int kk = k4 + u;
                const int gs = g ^ ((kk >> 3) & 15);
                *(unsigned*)&xT[kk * 136 + (gs << 3) + off] = pack_bf16x2(r0v[u], r1v[u]);
            }
        }
    }
    __syncthreads();

    const int l = t & 63, wave = t >> 6;
    const int lr = l & 15, lg = l >> 4;
    const int rr_a = wave * 16 + lr;
    const int r_g  = r0 + rr_a;
    const float* Arow = isL ? (lin_w + (size_t)r_g * 256)
                            : (lin_w + (size_t)(r_g - 256) * 256 + 128);
    bf16x8 af[4];
    #pragma unroll
    for (int kc = 0; kc < 4; ++kc) {
        const v4f a0 = *(const v4f*)(Arow + kc * 32 + lg * 8);
        const v4f a1 = *(const v4f*)(Arow + kc * 32 + lg * 8 + 4);
        unsigned p0 = pack_bf16x2(a0[0], a0[1]), p1 = pack_bf16x2(a0[2], a0[3]);
        unsigned p2 = pack_bf16x2(a1[0], a1[1]), p3 = pack_bf16x2(a1[2], a1[3]);
        af[kc] = __builtin_bit_cast(bf16x8, (uint4){p0, p1, p2, p3});
    }

    v4f acc[4];
    #pragma unroll
    for (int nf = 0; nf < 4; ++nf) acc[nf] = (v4f){0.f, 0.f, 0.f, 0.f};
    #pragma unroll
    for (int nf = 0; nf < 4; ++nf) {
        const int kk = nf * 16 + lr;
        const int vr = (kk >> 3) & 15;
        #pragma unroll
        for (int kc = 0; kc < 4; ++kc) {
            const bf16x8 bfv = *(const bf16x8*)&xT[kk * 136 + (((kc * 4 + lg) ^ vr) << 3)];
            acc[nf] = __builtin_amdgcn_mfma_f32_16x16x32_bf16(af[kc], bfv, acc[nf], 0, 0, 0);
        }
    }

    #pragma unroll
    for (int nf = 0; nf < 4; ++nf)
        #pragma unroll
        for (int j = 0; j < 4; ++j)
            Ps[(wave * 16 + lg * 4 + j) * 68 + nf * 16 + lr] = acc[nf][j];
    __syncthreads();

    #pragma unroll
    for (int q = 0; q < 4; ++q) {
        const int idx = t + q * 256;
        const int rr = idx >> 4, k4 = (idx & 15) << 2;
        const float lb = isL ? lin_b[r0 + rr] : 0.f;
        const v4f v = *(const v4f*)&Ps[rr * 68 + k4];
        float* dst = ws + ((size_t)(b * 512 + r0 + rr) * 128 + k0 + k4);
        *(v4f*)dst = (v4f){v[0] + lb, v[1] + lb, v[2] + lb, v[3] + lb};
    }
}

// ---------------- K2: 512-thr, 8-wave e-split + softmax + MFMA-PV ----------------
// grid (32 b, 8 it of 16 i-rows), 512 thr (8 waves = 2/SIMD).
#define RS0 0
#define RS1 8192
#define LT  16384
#define A6  20480
#define A4  20736
#define DLR 20992
#define DRR 21120
#define ATT 22144

__global__ __launch_bounds__(512) void k_attn(
    const float* __restrict__ x, const float* __restrict__ bias,
    const float* __restrict__ ws, float* __restrict__ out)
{
    __shared__ __align__(16) float S[23232];   // 90.75 KB

    const int t = threadIdx.x;
    const int b = blockIdx.x, it = blockIdx.y;
    const float* Pb = ws + (size_t)b * 65536;
    const float* Rsrc = Pb + 32768;

    v4f rx[4];
#define RLOAD(n_) do { const float* s_ = Rsrc + (n_) * 8192 + t * 4;  \
    _Pragma("unroll") for (int q = 0; q < 4; ++q)                     \
      rx[q] = *(const v4f*)(s_ + q * 2048); } while (0)

    RLOAD(0);

    {   // stage L^T tile [256 e][16 i] (coalesced)
        const float* Ls = Pb + it * 16;
        #pragma unroll
        for (int q = 0; q < 2; ++q) {
            const int idx = t + q * 512;
            const int e = idx >> 2, il4 = (idx & 3) * 4;
            *(v4f*)&S[LT + e * 16 + il4] = *(const v4f*)(Ls + e * 128 + il4);
        }
    }
    if (t < 256) S[A6 + t] = ws[WS_A6 + t];
    else         S[A4 + (t - 256)] = ws[WS_A4 + (t - 256)];

    const int l = t & 63, wv = t >> 6;         // wv = e-slice owner (8 slices)
    const int jl = l & 31, il = l >> 5;        // thread: 4 j x 8 i (il-half of 16)
    const int j0e = jl * 4;

    float acc[8][4] = {};                      // [i-sub][jj]  0.4a*|L+R|
    float dle[8] = {};                         // 0.6a*L per i-sub (wave's e-slice)
    float dre[4] = {};                         // 0.6a*R per jj   (wave's e-slice)

    #pragma unroll 1
    for (int c = 0; c < 4; ++c) {
        const int cur = c & 1;
        {   // commit chunk c (64 e x 128 j) to RS[cur]
            float* d_ = &S[RS0 + cur * 8192] + t * 4;
            #pragma unroll
            for (int q = 0; q < 4; ++q) *(v4f*)(d_ + q * 2048) = rx[q];
        }
        if (c < 3) RLOAD(c + 1);
        __syncthreads();

        const float* rs = &S[RS0 + cur * 8192];
        #pragma unroll
        for (int g = 0; g < 2; ++g) {
            const int er = wv * 8 + g * 4;     // e-row in chunk (wave's slice)
            const int eg = c * 64 + er;        // global e
            v4f rv[4], lA[4], lB[4];
            #pragma unroll
            for (int u = 0; u < 4; ++u) {
                rv[u] = *(const v4f*)&rs[(er + u) * 128 + j0e];
                lA[u] = *(const v4f*)&S[LT + (eg + u) * 16 + il * 8];
                lB[u] = *(const v4f*)&S[LT + (eg + u) * 16 + il * 8 + 4];
            }
            const v4f a6v = *(const v4f*)&S[A6 + eg];
            const v4f a4v = *(const v4f*)&S[A4 + eg];
            #pragma unroll
            for (int u = 0; u < 4; ++u) {
                const float a6u = a6v[u], a4u = a4v[u];
                #pragma unroll
                for (int q = 0; q < 4; ++q) {
                    const float la = lA[u][q], lb2 = lB[u][q];
                    dle[q]     = fmaf(a6u, la,  dle[q]);
                    dle[4 + q] = fmaf(a6u, lb2, dle[4 + q]);
                    #pragma unroll
                    for (int jj = 0; jj < 4; ++jj) {
                        const float r = rv[u][jj];
                        acc[q][jj]     = fmaf(a4u, fabsf(la  + r), acc[q][jj]);
                        acc[4 + q][jj] = fmaf(a4u, fabsf(lb2 + r), acc[4 + q][jj]);
                    }
                }
                #pragma unroll
                for (int jj = 0; jj < 4; ++jj)
                    dre[jj] = fmaf(a6u, rv[u][jj], dre[jj]);
            }
        }
    }
    __syncthreads();                           // all waves done reading RS0/RS1

    // ---- partials -> red[8][16][128] over RS0+RS1; DLR/DRR ----
    {
        float* red = &S[RS0];
        #pragma unroll
        for (int q = 0; q < 8; ++q)
            *(v4f*)&red[wv * 2048 + (il * 8 + q) * 128 + j0e] =
                (v4f){acc[q][0], acc[q][1], acc[q][2], acc[q][3]};
        if (jl == 0) {
            *(v4f*)&S[DLR + wv * 16 + il * 8]     = (v4f){dle[0], dle[1], dle[2], dle[3]};
            *(v4f*)&S[DLR + wv * 16 + il * 8 + 4] = (v4f){dle[4], dle[5], dle[6], dle[7]};
        }
        if (il == 0)
            *(v4f*)&S[DRR + wv * 128 + j0e] = (v4f){dre[0], dre[1], dre[2], dre[3]};
    }

    // issue xbf global loads NOW (latency hides under barrier + softmax)
    v4f xr[8];
    {
        const float* xg = x + b * 16384;
        #pragma unroll
        for (int q = 0; q < 4; ++q) {
            const int idx = t + q * 512;               // 0..2047
            const int w = idx >> 4, j8 = (idx & 15) * 8;
            xr[2 * q]     = *(const v4f*)(xg + w * 128 + j8);
            xr[2 * q + 1] = *(const v4f*)(xg + w * 128 + j8 + 4);
        }
    }
    __syncthreads();                                   // red/DLR/DRR ready

    // ---- softmax: thread = (i = t>>5, 4 j = (t&31)*4); row in 32-lane half ----
    {
        const int jps = t & 31, i = t >> 5;            // i in [0,16)
        const int j0s = jps * 4;
        const int i0 = it * 16;
        const float* red = &S[RS0];
        v4f sm = *(const v4f*)&red[i * 128 + j0s];
        v4f drs = *(const v4f*)&S[DRR + j0s];
        float dls = S[DLR + i];
        #pragma unroll
        for (int es = 1; es < 8; ++es) {
            sm  += *(const v4f*)&red[es * 2048 + i * 128 + j0s];
            drs += *(const v4f*)&S[DRR + es * 128 + j0s];
            dls += S[DLR + es * 16 + i];
        }
        const v4f bi = *(const v4f*)(bias + (i0 + i) * 128 + j0s);
        float ev[4];
        #pragma unroll
        for (int jj = 0; jj < 4; ++jj) ev[jj] = sm[jj] + dls + drs[jj] + bi[jj];
        float m_ = fmaxf(fmaxf(ev[0], ev[1]), fmaxf(ev[2], ev[3]));
        #pragma unroll
        for (int d = 1; d <= 16; d <<= 1) m_ = fmaxf(m_, __shfl_xor(m_, d));
        float p0 = __expf(ev[0] - m_), p1 = __expf(ev[1] - m_);
        float p2 = __expf(ev[2] - m_), p3 = __expf(ev[3] - m_);
        float s_ = p0 + p1 + p2 + p3;
        #pragma unroll
        for (int d = 1; d <= 16; d <<= 1) s_ += __shfl_xor(s_, d);
        const float inv = 1.f / s_;
        unsigned* attu = (unsigned*)&S[ATT];
        attu[i * 68 + jps * 2]     = pack_bf16x2(p0 * inv, p1 * inv);
        attu[i * 68 + jps * 2 + 1] = pack_bf16x2(p2 * inv, p3 * inv);
    }
    __syncthreads();                                   // red reads done -> RS1 free

    // ---- commit xbf[w][j] bf16 onto RS1 (+2KB spill into dead LT head) ----
    unsigned* ubf = (unsigned*)&S[RS1];
    #pragma unroll
    for (int q = 0; q < 4; ++q) {
        const int idx = t + q * 512;
        const int w = idx >> 4, jh = (idx & 15) * 4;   // u32 col
        const v4f x0 = xr[2 * q], x1 = xr[2 * q + 1];
        uint4 pk;
        pk.x = pack_bf16x2(x0[0], x0[1]);  pk.y = pack_bf16x2(x0[2], x0[3]);
        pk.z = pack_bf16x2(x1[0], x1[1]);  pk.w = pack_bf16x2(x1[2], x1[3]);
        *(uint4*)&ubf[w * 68 + jh] = pk;
    }
    __syncthreads();                                   // att + xbf ready

    // ---- PV via MFMA: out[w][i] = sum_j att[i][j] x[w][j]; D: m=i, n=w ----
    {
        const int lr = l & 15, lg = l >> 4;
        const int i0 = it * 16;
        const unsigned* attu = (const unsigned*)&S[ATT];
        bf16x8 paf[4];
        #pragma unroll
        for (int kc = 0; kc < 4; ++kc)
            paf[kc] = *(const bf16x8*)&attu[lr * 68 + kc * 16 + lg * 4];
        const int wrow = wv * 16 + lr;                 // 8 waves x 16 = 128 w
        v4f pacc = (v4f){0.f, 0.f, 0.f, 0.f};
        #pragma unroll
        for (int kc = 0; kc < 4; ++kc) {
            const bf16x8 bv = *(const bf16x8*)&ubf[wrow * 68 + kc * 16 + lg * 4];
            pacc = __builtin_amdgcn_mfma_f32_16x16x32_bf16(paf[kc], bv, pacc, 0, 0, 0);
        }
        v4f r;
        r[0] = 1.f / (1.f + __expf(-pacc[0]));
        r[1] = 1.f / (1.f + __expf(-pacc[1]));
        r[2] = 1.f / (1.f + __expf(-pacc[2]));
        r[3] = 1.f / (1.f + __expf(-pacc[3]));
        *(v4f*)(out + (size_t)b * 16384 + wrow * 128 + i0 + lg * 4) = r;
    }
}

extern "C" void kernel_launch(void* const* d_in, const int* in_sizes, int n_in,
                              void* d_out, int out_size, void* d_ws, size_t ws_size,
                              hipStream_t stream) {
    const float* x     = (const float*)d_in[0];
    const float* lin_w = (const float*)d_in[1];
    const float* lin_b = (const float*)d_in[2];
    const float* a     = (const float*)d_in[3];
    const float* bias  = (const float*)d_in[4];
    float* ws  = (float*)d_ws;
    float* out = (float*)d_out;

    k_linear<<<dim3(32, 8, 2), 256, 0, stream>>>(x, lin_w, lin_b, a, ws);
    k_attn  <<<dim3(32, 8), 512, 0, stream>>>(x, bias, ws, out);
}